// Round 1
// baseline (1300.357 us; speedup 1.0000x reference)
//
#include <hip/hip_runtime.h>
#include <stdint.h>

typedef uint32_t u32;
typedef uint64_t u64;

#define TPB   256
#define TILE  2048
#define SLOTS 8
#define RADIX 512
#define RBITS 9

__device__ __forceinline__ int clampi(int v, int lo, int hi){ return v < lo ? lo : (v > hi ? hi : v); }

__device__ __forceinline__ u32 expand10(u32 x){
  x &= 1023u;
  x = (x | (x << 16)) & 0x030000FFu;
  x = (x | (x << 8))  & 0x0300F00Fu;
  x = (x | (x << 4))  & 0x030C30C3u;
  x = (x | (x << 2))  & 0x09249249u;
  return x;
}
__device__ __forceinline__ u32 morton3(int gx, int gy, int gz){
  u32 x = (u32)clampi(gx, 0, 1023);
  u32 y = (u32)clampi(gy, 0, 1023);
  u32 z = (u32)clampi(gz, 0, 1023);
  return (expand10(x) << 2) | (expand10(y) << 1) | expand10(z);
}

// per-sphere geometry
struct Box { int a0,a1,a2,e0,e1,e2,nv; };
__device__ __forceinline__ Box boxOf(int i, const float* mn, const float* mx,
                                     float g0, float g1, float g2, float vs, int gs){
  Box b;
  int a0 = clampi((int)floorf((mn[3*i+0] - g0) / vs), 0, gs-1);
  int a1 = clampi((int)floorf((mn[3*i+1] - g1) / vs), 0, gs-1);
  int a2 = clampi((int)floorf((mn[3*i+2] - g2) / vs), 0, gs-1);
  int b0 = clampi((int)floorf((mx[3*i+0] - g0) / vs), 0, gs-1);
  int b1 = clampi((int)floorf((mx[3*i+1] - g1) / vs), 0, gs-1);
  int b2 = clampi((int)floorf((mx[3*i+2] - g2) / vs), 0, gs-1);
  b.a0=a0; b.a1=a1; b.a2=a2;
  b.e0=b0-a0+1; b.e1=b1-a1+1; b.e2=b2-a2+1;
  b.nv = b.e0*b.e1*b.e2;
  return b;
}

__global__ void countK(const float* mn, const float* mx, const float* gmin,
                       const float* vs_p, const int* gs_p, const int* T_p,
                       u32* counts, int* out_ovr, int M){
  int i = blockIdx.x * TPB + threadIdx.x;
  if (i >= M) return;
  float vs = vs_p[0]; int gs = gs_p[0]; int T = T_p[0];
  Box b = boxOf(i, mn, mx, gmin[0], gmin[1], gmin[2], vs, gs);
  int ovr = b.nv > T;
  counts[i] = ovr ? 0u : (u32)b.nv;
  out_ovr[i] = ovr;
}

// ---- scan of counts -> offsets (inclusive into out_off[g+1], then add block sums) ----
__global__ void scanAK(const u32* counts, int* out_off, u32* blockSums, int M){
  __shared__ u32 s[TPB];
  int b = blockIdx.x, t = threadIdx.x;
  int base = b * TILE + t * 8;
  u32 incl[8]; u32 run = 0;
  #pragma unroll
  for (int j = 0; j < 8; ++j){
    int g = base + j;
    u32 v = (g < M) ? counts[g] : 0u;
    run += v; incl[j] = run;
  }
  s[t] = run;
  __syncthreads();
  for (int o = 1; o < TPB; o <<= 1){
    u32 x = (t >= o) ? s[t-o] : 0u;
    __syncthreads();
    s[t] += x;
    __syncthreads();
  }
  u32 tbase = s[t] - run;
  #pragma unroll
  for (int j = 0; j < 8; ++j){
    int g = base + j;
    if (g < M) out_off[g+1] = (int)(tbase + incl[j]);
  }
  if (t == TPB-1) blockSums[b] = s[TPB-1];
}

__global__ void scanBK(u32* blockSums, int nb){
  __shared__ u32 s[TPB];
  int t = threadIdx.x;
  u32 run = 0;
  int nch = (nb + TPB - 1) / TPB;
  for (int c = 0; c < nch; ++c){
    int i = c * TPB + t;
    u32 v = (i < nb) ? blockSums[i] : 0u;
    s[t] = v;
    __syncthreads();
    for (int o = 1; o < TPB; o <<= 1){
      u32 x = (t >= o) ? s[t-o] : 0u;
      __syncthreads();
      s[t] += x;
      __syncthreads();
    }
    if (i < nb) blockSums[i] = run + s[t] - v;   // exclusive
    u32 tot = s[TPB-1];
    __syncthreads();
    run += tot;
  }
}

__global__ void scanCK(int* out_off, const u32* blockSums, int M, int* out_total){
  int b = blockIdx.x, t = threadIdx.x;
  u32 add = blockSums[b];
  int base = b * TILE + t * 8;
  #pragma unroll
  for (int j = 0; j < 8; ++j){
    int g = base + j;
    if (g < M){
      int v = out_off[g+1] + (int)add;
      out_off[g+1] = v;
      if (g == M-1) out_total[0] = v;
    }
  }
  if (b == 0 && t == 0) out_off[0] = 0;
}

// fill [total, MT) with sentinel-truncated morton (0) and sid -1
__global__ void tailK(int* out_m, int* out_s, const int* out_total, int MT){
  int total = *out_total;
  int base = blockIdx.x * TILE + threadIdx.x;
  #pragma unroll
  for (int s = 0; s < SLOTS; ++s){
    int j = base + s * TPB;
    if (j < MT && j >= total){ out_m[j] = 0; out_s[j] = -1; }
  }
}

__global__ void genK(const float* mn, const float* mx, const float* gmin,
                     const float* vs_p, const int* gs_p, const int* T_p,
                     const int* out_off, u32* keyA, u32* sidA, int M){
  int i = blockIdx.x * TPB + threadIdx.x;
  if (i >= M) return;
  float vs = vs_p[0]; int gs = gs_p[0]; int T = T_p[0];
  Box b = boxOf(i, mn, mx, gmin[0], gmin[1], gmin[2], vs, gs);
  if (b.nv > T) return;
  int base = out_off[i];
  int k = 0;
  for (int dx = 0; dx < b.e0; ++dx)
    for (int dy = 0; dy < b.e1; ++dy)
      for (int dz = 0; dz < b.e2; ++dz){
        keyA[base + k] = morton3(b.a0 + dx, b.a1 + dy, b.a2 + dz);
        sidA[base + k] = (u32)i;
        ++k;
      }
}

// ---- radix pass kernels ----
__global__ void histK(const u32* keys, u32* hist, u32* digitTotal,
                      const int* out_total, int maxTiles, int shift){
  __shared__ u32 cnt[RADIX];
  int tile = blockIdx.x, t = threadIdx.x;
  int total = *out_total;
  int numTiles = (total + TILE - 1) / TILE;
  if (tile >= numTiles) return;
  cnt[t] = 0; cnt[t + TPB] = 0;
  __syncthreads();
  int base = tile * TILE;
  #pragma unroll
  for (int s = 0; s < SLOTS; ++s){
    int j = base + s * TPB + t;
    if (j < total) atomicAdd(&cnt[(keys[j] >> shift) & (RADIX-1)], 1u);
  }
  __syncthreads();
  for (int d = t; d < RADIX; d += TPB){
    hist[(size_t)d * maxTiles + tile] = cnt[d];
    if (cnt[d]) atomicAdd(&digitTotal[d], cnt[d]);
  }
}

__global__ void scanDigitsK(const u32* digitTotal, u32* digitBase){
  __shared__ u32 s[RADIX];
  int t = threadIdx.x;
  u32 v = digitTotal[t];
  s[t] = v;
  __syncthreads();
  for (int o = 1; o < RADIX; o <<= 1){
    u32 x = (t >= o) ? s[t-o] : 0u;
    __syncthreads();
    s[t] += x;
    __syncthreads();
  }
  digitBase[t] = s[t] - v;   // exclusive
}

__global__ void tilePrefixK(u32* hist, const u32* digitBase,
                            const int* out_total, int maxTiles){
  __shared__ u32 s[TPB];
  int d = blockIdx.x, t = threadIdx.x;
  int total = *out_total;
  int numTiles = (total + TILE - 1) / TILE;
  u32 running = digitBase[d];
  int nch = (numTiles + TPB - 1) / TPB;
  for (int c = 0; c < nch; ++c){
    int i = c * TPB + t;
    u32 v = (i < numTiles) ? hist[(size_t)d * maxTiles + i] : 0u;
    s[t] = v;
    __syncthreads();
    for (int o = 1; o < TPB; o <<= 1){
      u32 x = (t >= o) ? s[t-o] : 0u;
      __syncthreads();
      s[t] += x;
      __syncthreads();
    }
    if (i < numTiles) hist[(size_t)d * maxTiles + i] = running + s[t] - v;
    u32 tot = s[TPB-1];
    __syncthreads();
    running += tot;
  }
}

__global__ void scatterK(const u32* keyIn, const u32* sidIn, u32* keyOut, u32* sidOut,
                         const u32* hist, const int* out_total, int maxTiles, int shift){
  __shared__ u32 baseS[RADIX];
  __shared__ u32 wcnt[4 * RADIX];
  __shared__ u32 running[RADIX];
  int tile = blockIdx.x, t = threadIdx.x;
  int total = *out_total;
  int numTiles = (total + TILE - 1) / TILE;
  if (tile >= numTiles) return;
  for (int d = t; d < RADIX; d += TPB){
    baseS[d] = hist[(size_t)d * maxTiles + tile];
    running[d] = 0;
  }
  int lane = t & 63, wave = t >> 6;
  u64 lt = (1ull << lane) - 1ull;
  int tbase = tile * TILE;
  for (int slot = 0; slot < SLOTS; ++slot){
    int idx = tbase + slot * TPB + t;
    bool valid = idx < total;
    u32 key = 0, sid = 0; int d = 0;
    if (valid){ key = keyIn[idx]; sid = sidIn[idx]; d = (int)((key >> shift) & (RADIX-1)); }
    // zero per-wave counters
    for (int i = t; i < 4 * RADIX; i += TPB) wcnt[i] = 0;
    __syncthreads();
    u64 active = __ballot(valid);
    u64 mask = active;
    #pragma unroll
    for (int b = 0; b < RBITS; ++b){
      u64 bal = __ballot((d >> b) & 1);
      mask &= ((d >> b) & 1) ? bal : ~bal;
    }
    int wrank = __popcll(mask & lt);
    if (valid && ((mask & lt) == 0ull)) wcnt[wave * RADIX + d] = (u32)__popcll(mask);
    __syncthreads();
    if (valid){
      u32 r = running[d] + (u32)wrank;
      for (int w = 0; w < wave; ++w) r += wcnt[w * RADIX + d];
      u32 pos = baseS[d] + r;
      keyOut[pos] = key;
      sidOut[pos] = sid;
    }
    __syncthreads();
    for (int dd = t; dd < RADIX; dd += TPB)
      running[dd] += wcnt[dd] + wcnt[RADIX + dd] + wcnt[2*RADIX + dd] + wcnt[3*RADIX + dd];
    __syncthreads();
  }
}

extern "C" void kernel_launch(void* const* d_in, const int* in_sizes, int n_in,
                              void* d_out, int out_size, void* d_ws, size_t ws_size,
                              hipStream_t stream){
  const float* mn   = (const float*)d_in[0];
  const float* mx   = (const float*)d_in[1];
  const float* gmin = (const float*)d_in[2];
  const float* vs   = (const float*)d_in[3];
  const int*   gs   = (const int*)d_in[4];
  const int*   T_p  = (const int*)d_in[5];

  int M = in_sizes[0] / 3;
  long long S = (long long)out_size - 2LL*M - 2LL;
  int T = (int)(S / (2LL*M));               // pairs_morton stored 1 int32 slot per element
  int MT = (int)((long long)M * T);

  int* out_m     = (int*)d_out;
  int* out_s     = out_m + MT;
  int* out_off   = out_s + MT;
  int* out_ovr   = out_off + (M + 1);
  int* out_total = out_ovr + M;

  // workspace layout
  uint8_t* w = (uint8_t*)d_ws;
  size_t off = 0;
  auto alloc = [&](size_t bytes) -> void* {
    size_t p = (off + 255) & ~(size_t)255;
    off = p + bytes;
    return (void*)(w + p);
  };
  int nbA = (M + TILE - 1) / TILE;
  u32* counts     = (u32*)alloc((size_t)M * 4);
  u32* blockSums  = (u32*)alloc((size_t)nbA * 4);
  u32* digitTotal = (u32*)alloc(RADIX * 4);
  u32* digitBase  = (u32*)alloc(RADIX * 4);
  size_t fixed = off + 4096;
  size_t avail = ws_size > fixed ? ws_size - fixed : 0;
  long long cap = (long long)(avail / 9) & ~(long long)(TILE - 1);  // 8B (keyA+sidA) + 1B hist per elem
  if (cap > MT) cap = MT;
  if (cap < TILE) cap = TILE;
  int maxTiles = (int)(cap / TILE);
  u32* keyA = (u32*)alloc((size_t)cap * 4);
  u32* sidA = (u32*)alloc((size_t)cap * 4);
  u32* hist = (u32*)alloc((size_t)RADIX * maxTiles * 4);

  u32* keyB = (u32*)out_m;
  u32* sidB = (u32*)out_s;

  int gM = (M + TPB - 1) / TPB;

  countK<<<gM, TPB, 0, stream>>>(mn, mx, gmin, vs, gs, T_p, counts, out_ovr, M);
  scanAK<<<nbA, TPB, 0, stream>>>(counts, out_off, blockSums, M);
  scanBK<<<1, TPB, 0, stream>>>(blockSums, nbA);
  scanCK<<<nbA, TPB, 0, stream>>>(out_off, blockSums, M, out_total);
  tailK<<<(MT + TILE - 1) / TILE, TPB, 0, stream>>>(out_m, out_s, out_total, MT);
  genK<<<gM, TPB, 0, stream>>>(mn, mx, gmin, vs, gs, T_p, out_off, keyA, sidA, M);

  struct Pass { const u32 *ki, *si; u32 *ko, *so; int sh; };
  Pass P[3] = {
    { keyA, sidA, keyB, sidB, 0 },
    { keyB, sidB, keyA, sidA, RBITS },
    { keyA, sidA, keyB, sidB, 2 * RBITS },
  };
  for (int p = 0; p < 3; ++p){
    hipMemsetAsync(digitTotal, 0, RADIX * 4, stream);
    histK<<<maxTiles, TPB, 0, stream>>>(P[p].ki, hist, digitTotal, out_total, maxTiles, P[p].sh);
    scanDigitsK<<<1, RADIX, 0, stream>>>(digitTotal, digitBase);
    tilePrefixK<<<RADIX, TPB, 0, stream>>>(hist, digitBase, out_total, maxTiles);
    scatterK<<<maxTiles, TPB, 0, stream>>>(P[p].ki, P[p].si, P[p].ko, P[p].so, hist, out_total, maxTiles, P[p].sh);
  }
}

// Round 2
// 643.212 us; speedup vs baseline: 2.0217x; 2.0217x over previous
//
#include <hip/hip_runtime.h>
#include <stdint.h>

typedef uint32_t u32;
typedef uint64_t u64;

#define TPB   256
#define TILE  2048      // for scan/tail kernels (TPB*8)
#define SLOTS 8
#define RADIX 512
#define RBITS 9

#define STILE 4096      // sort tile
#define SSLOT 16        // slots per wave chunk: chunk = 1024 = SSLOT*64

__device__ __forceinline__ int clampi(int v, int lo, int hi){ return v < lo ? lo : (v > hi ? hi : v); }

__device__ __forceinline__ u32 expand10(u32 x){
  x &= 1023u;
  x = (x | (x << 16)) & 0x030000FFu;
  x = (x | (x << 8))  & 0x0300F00Fu;
  x = (x | (x << 4))  & 0x030C30C3u;
  x = (x | (x << 2))  & 0x09249249u;
  return x;
}
__device__ __forceinline__ u32 morton3(int gx, int gy, int gz){
  u32 x = (u32)clampi(gx, 0, 1023);
  u32 y = (u32)clampi(gy, 0, 1023);
  u32 z = (u32)clampi(gz, 0, 1023);
  return (expand10(x) << 2) | (expand10(y) << 1) | expand10(z);
}

struct Box { int a0,a1,a2,e0,e1,e2,nv; };
__device__ __forceinline__ Box boxOf(int i, const float* mn, const float* mx,
                                     float g0, float g1, float g2, float vs, int gs){
  Box b;
  int a0 = clampi((int)floorf((mn[3*i+0] - g0) / vs), 0, gs-1);
  int a1 = clampi((int)floorf((mn[3*i+1] - g1) / vs), 0, gs-1);
  int a2 = clampi((int)floorf((mn[3*i+2] - g2) / vs), 0, gs-1);
  int b0 = clampi((int)floorf((mx[3*i+0] - g0) / vs), 0, gs-1);
  int b1 = clampi((int)floorf((mx[3*i+1] - g1) / vs), 0, gs-1);
  int b2 = clampi((int)floorf((mx[3*i+2] - g2) / vs), 0, gs-1);
  b.a0=a0; b.a1=a1; b.a2=a2;
  b.e0=b0-a0+1; b.e1=b1-a1+1; b.e2=b2-a2+1;
  b.nv = b.e0*b.e1*b.e2;
  return b;
}

__global__ void countK(const float* mn, const float* mx, const float* gmin,
                       const float* vs_p, const int* gs_p, const int* T_p,
                       u32* counts, int* out_ovr, int M){
  int i = blockIdx.x * TPB + threadIdx.x;
  if (i >= M) return;
  float vs = vs_p[0]; int gs = gs_p[0]; int T = T_p[0];
  Box b = boxOf(i, mn, mx, gmin[0], gmin[1], gmin[2], vs, gs);
  int ovr = b.nv > T;
  counts[i] = ovr ? 0u : (u32)b.nv;
  out_ovr[i] = ovr;
}

__global__ void scanAK(const u32* counts, int* out_off, u32* blockSums, int M){
  __shared__ u32 s[TPB];
  int b = blockIdx.x, t = threadIdx.x;
  int base = b * TILE + t * 8;
  u32 incl[8]; u32 run = 0;
  #pragma unroll
  for (int j = 0; j < 8; ++j){
    int g = base + j;
    u32 v = (g < M) ? counts[g] : 0u;
    run += v; incl[j] = run;
  }
  s[t] = run;
  __syncthreads();
  for (int o = 1; o < TPB; o <<= 1){
    u32 x = (t >= o) ? s[t-o] : 0u;
    __syncthreads();
    s[t] += x;
    __syncthreads();
  }
  u32 tbase = s[t] - run;
  #pragma unroll
  for (int j = 0; j < 8; ++j){
    int g = base + j;
    if (g < M) out_off[g+1] = (int)(tbase + incl[j]);
  }
  if (t == TPB-1) blockSums[b] = s[TPB-1];
}

__global__ void scanBK(u32* blockSums, int nb){
  __shared__ u32 s[TPB];
  int t = threadIdx.x;
  u32 run = 0;
  int nch = (nb + TPB - 1) / TPB;
  for (int c = 0; c < nch; ++c){
    int i = c * TPB + t;
    u32 v = (i < nb) ? blockSums[i] : 0u;
    s[t] = v;
    __syncthreads();
    for (int o = 1; o < TPB; o <<= 1){
      u32 x = (t >= o) ? s[t-o] : 0u;
      __syncthreads();
      s[t] += x;
      __syncthreads();
    }
    if (i < nb) blockSums[i] = run + s[t] - v;
    u32 tot = s[TPB-1];
    __syncthreads();
    run += tot;
  }
}

__global__ void scanCK(int* out_off, const u32* blockSums, int M, int* out_total){
  int b = blockIdx.x, t = threadIdx.x;
  u32 add = blockSums[b];
  int base = b * TILE + t * 8;
  #pragma unroll
  for (int j = 0; j < 8; ++j){
    int g = base + j;
    if (g < M){
      int v = out_off[g+1] + (int)add;
      out_off[g+1] = v;
      if (g == M-1) out_total[0] = v;
    }
  }
  if (b == 0 && t == 0) out_off[0] = 0;
}

__global__ void tailK(int* out_m, int* out_s, const int* out_total, int MT){
  int total = *out_total;
  int base = blockIdx.x * TILE + threadIdx.x;
  #pragma unroll
  for (int s = 0; s < SLOTS; ++s){
    int j = base + s * TPB;
    if (j < MT && j >= total){ out_m[j] = 0; out_s[j] = -1; }
  }
}

// generate packed (morton<<32 | sid) compacted at offsets
__global__ void genK(const float* mn, const float* mx, const float* gmin,
                     const float* vs_p, const int* gs_p, const int* T_p,
                     const int* out_off, u64* buf, int M){
  int i = blockIdx.x * TPB + threadIdx.x;
  if (i >= M) return;
  float vs = vs_p[0]; int gs = gs_p[0]; int T = T_p[0];
  Box b = boxOf(i, mn, mx, gmin[0], gmin[1], gmin[2], vs, gs);
  if (b.nv > T) return;
  int base = out_off[i];
  int k = 0;
  for (int dx = 0; dx < b.e0; ++dx)
    for (int dy = 0; dy < b.e1; ++dy)
      for (int dz = 0; dz < b.e2; ++dz){
        u32 m = morton3(b.a0 + dx, b.a1 + dy, b.a2 + dz);
        buf[base + k] = ((u64)m << 32) | (u32)i;
        ++k;
      }
}

// histogram over packed keys (hi word), tiles of STILE
__global__ void histK(const u64* in, u32* hist, u32* digitTotal,
                      const int* total_p, int maxTiles, int shift){
  __shared__ u32 cnt[RADIX];
  int tile = blockIdx.x, t = threadIdx.x;
  int total = *total_p;
  int numTiles = (total + STILE - 1) / STILE;
  if (tile >= numTiles) return;
  cnt[t] = 0; cnt[t + TPB] = 0;
  __syncthreads();
  const u32* hi = (const u32*)in;
  int base = tile * STILE;
  #pragma unroll
  for (int s = 0; s < STILE / TPB; ++s){
    int j = base + s * TPB + t;
    if (j < total) atomicAdd(&cnt[(hi[2*j+1] >> shift) & (RADIX-1)], 1u);
  }
  __syncthreads();
  for (int d = t; d < RADIX; d += TPB){
    hist[(size_t)d * maxTiles + tile] = cnt[d];
    if (cnt[d]) atomicAdd(&digitTotal[d], cnt[d]);
  }
}

__global__ void scanDigitsK(const u32* digitTotal, u32* digitBase){
  __shared__ u32 s[RADIX];
  int t = threadIdx.x;
  u32 v = digitTotal[t];
  s[t] = v;
  __syncthreads();
  for (int o = 1; o < RADIX; o <<= 1){
    u32 x = (t >= o) ? s[t-o] : 0u;
    __syncthreads();
    s[t] += x;
    __syncthreads();
  }
  digitBase[t] = s[t] - v;
}

__global__ void tilePrefixK(u32* hist, const u32* digitBase,
                            const int* total_p, int maxTiles){
  __shared__ u32 s[TPB];
  int d = blockIdx.x, t = threadIdx.x;
  int total = *total_p;
  int numTiles = (total + STILE - 1) / STILE;
  u32 running = digitBase[d];
  int nch = (numTiles + TPB - 1) / TPB;
  for (int c = 0; c < nch; ++c){
    int i = c * TPB + t;
    u32 v = (i < numTiles) ? hist[(size_t)d * maxTiles + i] : 0u;
    s[t] = v;
    __syncthreads();
    for (int o = 1; o < TPB; o <<= 1){
      u32 x = (t >= o) ? s[t-o] : 0u;
      __syncthreads();
      s[t] += x;
      __syncthreads();
    }
    if (i < numTiles) hist[(size_t)d * maxTiles + i] = running + s[t] - v;
    u32 tot = s[TPB-1];
    __syncthreads();
    running += tot;
  }
}

// staged scatter: rank in LDS, stage tile sorted in LDS, write coalesced runs.
// split==0: write packed u64 to outP. split==1: write key->outM, sid->outS.
__global__ void scatterK(const u64* in, u64* outP, u32* outM, u32* outS,
                         const u32* hist, const int* total_p, int maxTiles,
                         int shift, int split){
  __shared__ u64 stage[STILE];                 // 32 KB
  __shared__ u32 wHist[4 * RADIX];             // 8 KB  [wave][digit]
  __shared__ u32 start[RADIX];                 // 2 KB  tile-local digit starts
  __shared__ u32 baseS[RADIX];                 // 2 KB  global digit bases for tile
  __shared__ u32 tmp[TPB];                     // 1 KB

  int tile = blockIdx.x, t = threadIdx.x;
  int total = *total_p;
  int numTiles = (total + STILE - 1) / STILE;
  if (tile >= numTiles) return;
  int lane = t & 63, wave = t >> 6;
  u64 lt = (1ull << lane) - 1ull;

  for (int i = t; i < 4 * RADIX; i += TPB) wHist[i] = 0;
  for (int d = t; d < RADIX; d += TPB) baseS[d] = hist[(size_t)d * maxTiles + tile];
  __syncthreads();

  int tbase = tile * STILE;
  int cbase = tbase + (wave << 10);            // wave-private contiguous chunk of 1024
  u32* wh = &wHist[wave << 9];

  u64 relem[SSLOT];
  u32 rrd[SSLOT];                              // (rankInWave<<16) | digit

  // Phase A: load + stable rank within wave (order: wave, slot, lane == index order)
  #pragma unroll
  for (int s = 0; s < SSLOT; ++s){
    int idx = cbase + (s << 6) + lane;
    bool valid = idx < total;
    u64 e = valid ? in[idx] : 0ull;
    int d = (int)((u32)(e >> 32) >> shift) & (RADIX - 1);
    u64 mask = __ballot(valid);
    #pragma unroll
    for (int b = 0; b < RBITS; ++b){
      u64 bal = __ballot((d >> b) & 1);
      mask &= ((d >> b) & 1) ? bal : ~bal;
    }
    u32 lr = (u32)__popcll(mask & lt);
    u32 old = valid ? wh[d] : 0u;
    if (valid && ((mask & lt) == 0ull)) wh[d] = old + (u32)__popcll(mask);
    relem[s] = e;
    rrd[s] = ((old + lr) << 16) | (u32)d;
  }
  __syncthreads();

  // Phase B: wave-exclusive offsets + tile-local digit scan
  for (int d = t; d < RADIX; d += TPB){
    u32 c0 = wHist[d], c1 = wHist[RADIX + d], c2 = wHist[2*RADIX + d], c3 = wHist[3*RADIX + d];
    wHist[d] = 0; wHist[RADIX + d] = c0; wHist[2*RADIX + d] = c0 + c1; wHist[3*RADIX + d] = c0 + c1 + c2;
    start[d] = c0 + c1 + c2 + c3;
  }
  __syncthreads();
  u32 a0 = start[2*t], a1 = start[2*t + 1];
  u32 sum = a0 + a1;
  tmp[t] = sum;
  __syncthreads();
  for (int o = 1; o < TPB; o <<= 1){
    u32 x = (t >= o) ? tmp[t-o] : 0u;
    __syncthreads();
    tmp[t] += x;
    __syncthreads();
  }
  u32 excl = tmp[t] - sum;
  start[2*t] = excl;
  start[2*t + 1] = excl + a0;
  __syncthreads();

  // Phase C: stage into LDS at tile-sorted position
  #pragma unroll
  for (int s = 0; s < SSLOT; ++s){
    int idx = cbase + (s << 6) + lane;
    if (idx < total){
      u32 rd = rrd[s];
      u32 d = rd & (RADIX - 1);
      u32 pos = start[d] + wh[d] + (rd >> 16);
      stage[pos] = relem[s];
    }
  }
  __syncthreads();

  // Phase D: linear LDS read, coalesced-run global write
  int tileElems = total - tbase; if (tileElems > STILE) tileElems = STILE;
  if (split){
    for (int j = t; j < tileElems; j += TPB){
      u64 e = stage[j];
      u32 key = (u32)(e >> 32);
      int d = (int)((key >> shift) & (RADIX - 1));
      int dest = (int)(baseS[d] + (u32)j - start[d]);
      outM[dest] = key;
      outS[dest] = (u32)e;
    }
  } else {
    for (int j = t; j < tileElems; j += TPB){
      u64 e = stage[j];
      int d = (int)((u32)(e >> 32) >> shift) & (RADIX - 1);
      int dest = (int)(baseS[d] + (u32)j - start[d]);
      outP[dest] = e;
    }
  }
}

extern "C" void kernel_launch(void* const* d_in, const int* in_sizes, int n_in,
                              void* d_out, int out_size, void* d_ws, size_t ws_size,
                              hipStream_t stream){
  const float* mn   = (const float*)d_in[0];
  const float* mx   = (const float*)d_in[1];
  const float* gmin = (const float*)d_in[2];
  const float* vs   = (const float*)d_in[3];
  const int*   gs   = (const int*)d_in[4];
  const int*   T_p  = (const int*)d_in[5];

  int M = in_sizes[0] / 3;
  long long S = (long long)out_size - 2LL*M - 2LL;
  int T = (int)(S / (2LL*M));
  int MT = (int)((long long)M * T);

  int* out_m     = (int*)d_out;
  int* out_s     = out_m + MT;
  int* out_off   = out_s + MT;
  int* out_ovr   = out_off + (M + 1);
  int* out_total = out_ovr + M;

  uint8_t* w = (uint8_t*)d_ws;
  size_t off = 0;
  auto alloc = [&](size_t bytes) -> void* {
    size_t p = (off + 255) & ~(size_t)255;
    off = p + bytes;
    return (void*)(w + p);
  };
  int nbA = (M + TILE - 1) / TILE;
  u32* counts     = (u32*)alloc((size_t)M * 4);
  u32* blockSums  = (u32*)alloc((size_t)nbA * 4);
  u32* digitTotal = (u32*)alloc(RADIX * 4);
  u32* digitBase  = (u32*)alloc(RADIX * 4);
  size_t fixed = off + 4096;
  size_t avail = ws_size > fixed ? ws_size - fixed : 0;
  long long cap = (long long)(avail / 9) & ~(long long)(STILE - 1);  // 8B packed + 0.5B hist per elem
  if (cap > MT) cap = MT;
  if (cap < STILE) cap = STILE;
  int maxTiles = (int)(cap / STILE);
  u64* bufA = (u64*)alloc((size_t)cap * 8);
  u32* hist = (u32*)alloc((size_t)RADIX * maxTiles * 4);

  u64* bufB = (u64*)d_out;   // u64[0..total) lives in bytes [0, 8*total) <= 8*MT of d_out

  int gM = (M + TPB - 1) / TPB;

  countK<<<gM, TPB, 0, stream>>>(mn, mx, gmin, vs, gs, T_p, counts, out_ovr, M);
  scanAK<<<nbA, TPB, 0, stream>>>(counts, out_off, blockSums, M);
  scanBK<<<1, TPB, 0, stream>>>(blockSums, nbA);
  scanCK<<<nbA, TPB, 0, stream>>>(out_off, blockSums, M, out_total);
  genK<<<gM, TPB, 0, stream>>>(mn, mx, gmin, vs, gs, T_p, out_off, bufA, M);

  // pass 0: A -> B(d_out region)
  hipMemsetAsync(digitTotal, 0, RADIX * 4, stream);
  histK<<<maxTiles, TPB, 0, stream>>>(bufA, hist, digitTotal, out_total, maxTiles, 0);
  scanDigitsK<<<1, RADIX, 0, stream>>>(digitTotal, digitBase);
  tilePrefixK<<<RADIX, TPB, 0, stream>>>(hist, digitBase, out_total, maxTiles);
  scatterK<<<maxTiles, TPB, 0, stream>>>(bufA, bufB, nullptr, nullptr, hist, out_total, maxTiles, 0, 0);

  // pass 1: B -> A
  hipMemsetAsync(digitTotal, 0, RADIX * 4, stream);
  histK<<<maxTiles, TPB, 0, stream>>>(bufB, hist, digitTotal, out_total, maxTiles, RBITS);
  scanDigitsK<<<1, RADIX, 0, stream>>>(digitTotal, digitBase);
  tilePrefixK<<<RADIX, TPB, 0, stream>>>(hist, digitBase, out_total, maxTiles);
  scatterK<<<maxTiles, TPB, 0, stream>>>(bufB, bufA, nullptr, nullptr, hist, out_total, maxTiles, RBITS, 0);

  // tail fill after last read of B (d_out region)
  tailK<<<(MT + TILE - 1) / TILE, TPB, 0, stream>>>(out_m, out_s, out_total, MT);

  // pass 2: A -> final split outputs
  hipMemsetAsync(digitTotal, 0, RADIX * 4, stream);
  histK<<<maxTiles, TPB, 0, stream>>>(bufA, hist, digitTotal, out_total, maxTiles, 2 * RBITS);
  scanDigitsK<<<1, RADIX, 0, stream>>>(digitTotal, digitBase);
  tilePrefixK<<<RADIX, TPB, 0, stream>>>(hist, digitBase, out_total, maxTiles);
  scatterK<<<maxTiles, TPB, 0, stream>>>(bufA, nullptr, (u32*)out_m, (u32*)out_s, hist, out_total, maxTiles, 2 * RBITS, 1);
}